// Round 1
// baseline (1401.856 us; speedup 1.0000x reference)
//
#include <hip/hip_runtime.h>
#include <math.h>

// LaplacianLoss: out[b] = vertex_weight * ||L @ x[b]||_F * NV
// L: 10000x10000 fp32, streamed once (~400 MB from HBM; poison evicts L3).
// Round-3 structure: barrier-free streaming skinny GEMM.
//  - NO LDS in the main loop: x slices are 16B-aligned in global
//    (byte off = 12*(b*10000+col0), col0 % 4 == 0), so each lane reads its
//    12 x-floats as 3 aligned float4s straight from L2 (x = 960 KB, resident).
//  - L fragments register-prefetched one tile ahead -> the 400 MB L stream
//    pipelines across tiles with zero barriers (compiler can't hoist loads
//    over __syncthreads; now there are none in the loop).
//  - grid = 625 row-groups x 4 j-groups; wave owns 4 rows, lane owns 4 cols.
//  - partials atomicAdd'ed into C[10000][24] (sum over j BEFORE squaring),
//    lap_reduce squares + reduces + sqrt. Epilogue LDS transpose unchanged.

#define NVERT 10000
#define TJ 256
#define TPG 10
#define JG 4
#define RPW 4         // rows per wave
#define RPB 16        // rows per block (4 waves)
#define NROWG 625
#define GRID1 (NROWG * JG)
#define GRID2 40

__global__ __launch_bounds__(256, 3) void lap_main(
    const float* __restrict__ x, const float* __restrict__ L,
    float* __restrict__ C) {
  __shared__ __align__(16) float smem[6400];  // epilogue transpose only

  const int tid  = threadIdx.x;
  const int lane = tid & 63;
  const int wave = tid >> 6;
  const int rg   = blockIdx.x >> 2;   // row-group
  const int jg   = blockIdx.x & 3;    // j-group
  const int row0 = rg * RPB + wave * RPW;

  __align__(16) float acc[RPW][24];
#pragma unroll
  for (int r = 0; r < RPW; ++r)
#pragma unroll
    for (int n = 0; n < 24; ++n) acc[r][n] = 0.f;

  const int jbase = jg * (TPG * TJ);
  const int ntF   = (jg == JG - 1) ? (TPG - 1) : TPG;  // full 256-col tiles

  const float* Lp  = L + (long)row0 * NVERT + jbase + 4 * lane;
  const float* xp0 = x + (long)(jbase + 4 * lane) * 3;

  // ---- register double-buffer for L fragments (4 rows x float4) ----
  __align__(16) float Lv[RPW][4], Ln[RPW][4];
#pragma unroll
  for (int r = 0; r < RPW; ++r)
    *(float4*)&Lv[r][0] = *(const float4*)(Lp + (long)r * NVERT);

  for (int t = 0; t < ntF; ++t) {
    // prefetch next tile's L fragments (uniform branch)
    if (t + 1 < ntF) {
#pragma unroll
      for (int r = 0; r < RPW; ++r)
        *(float4*)&Ln[r][0] =
            *(const float4*)(Lp + (long)r * NVERT + (t + 1) * TJ);
    }

    const float* xp = xp0 + (long)t * (TJ * 3);
#pragma unroll
    for (int b = 0; b < 8; ++b) {
      __align__(16) float xv[12];
      *(float4*)&xv[0] = *(const float4*)(xp + (long)b * 30000);
      *(float4*)&xv[4] = *(const float4*)(xp + (long)b * 30000 + 4);
      *(float4*)&xv[8] = *(const float4*)(xp + (long)b * 30000 + 8);
#pragma unroll
      for (int r = 0; r < RPW; ++r)
#pragma unroll
        for (int jj = 0; jj < 4; ++jj)
#pragma unroll
          for (int k = 0; k < 3; ++k)
            acc[r][b * 3 + k] += Lv[r][jj] * xv[jj * 3 + k];
    }

    if (t + 1 < ntF) {
#pragma unroll
      for (int r = 0; r < RPW; ++r)
#pragma unroll
        for (int jj = 0; jj < 4; ++jj) Lv[r][jj] = Ln[r][jj];
    }
  }

  // ---- tail: columns 9984..9999 (jg==3 only), 16 lanes x 1 column ----
  if (jg == JG - 1 && lane < 16) {
    const int col = jbase + (TPG - 1) * TJ + lane;
    float Lt[RPW];
#pragma unroll
    for (int r = 0; r < RPW; ++r)
      Lt[r] = L[(long)(row0 + r) * NVERT + col];
#pragma unroll
    for (int b = 0; b < 8; ++b) {
      const float* xb = x + (long)(b * NVERT + col) * 3;
      const float x0 = xb[0], x1 = xb[1], x2 = xb[2];
#pragma unroll
      for (int r = 0; r < RPW; ++r) {
        acc[r][b * 3 + 0] += Lt[r] * x0;
        acc[r][b * 3 + 1] += Lt[r] * x1;
        acc[r][b * 3 + 2] += Lt[r] * x2;
      }
    }
  }

  // ---- epilogue: cross-lane sum per (row, n), atomic into C ----
  // 4 rounds; wave w dumps 64 lanes x 96 floats at stride 100 (conflict-free:
  // 100 mod 32 = 4 -> 8 lanes cover all 32 banks), threads<96 sum 64 lanes.
  for (int w = 0; w < 4; ++w) {
    __syncthreads();
    if (wave == w) {
#pragma unroll
      for (int r = 0; r < RPW; ++r)
#pragma unroll
        for (int c = 0; c < 6; ++c)
          *(float4*)&smem[lane * 100 + r * 24 + c * 4] = *(float4*)&acc[r][c * 4];
    }
    __syncthreads();
    if (tid < 96) {
      float s = 0.f;
#pragma unroll
      for (int l = 0; l < 64; ++l) s += smem[l * 100 + tid];
      const int row = rg * RPB + w * RPW + tid / 24;
      atomicAdd(&C[row * 24 + (tid % 24)], s);
    }
  }
}

__global__ __launch_bounds__(256) void lap_reduce(
    const float* __restrict__ C, const float* __restrict__ wv,
    float* __restrict__ out, float* __restrict__ Sg, unsigned* __restrict__ ctr) {
  __shared__ float sS[8];
  const int tid = threadIdx.x;
  if (tid < 8) sS[tid] = 0.f;
  __syncthreads();

  const int row = blockIdx.x * 256 + tid;  // one row per thread (10240 >= 10000)
  float pb[8] = {0.f, 0.f, 0.f, 0.f, 0.f, 0.f, 0.f, 0.f};
  if (row < NVERT) {
    const float* rp = C + (long)row * 24;
#pragma unroll
    for (int b = 0; b < 8; ++b) {
      float s = 0.f;
#pragma unroll
      for (int k = 0; k < 3; ++k) {
        float v = rp[b * 3 + k];
        s += v * v;
      }
      pb[b] = s;
    }
  }
#pragma unroll
  for (int b = 0; b < 8; ++b) atomicAdd(&sS[b], pb[b]);
  __syncthreads();
  if (tid < 8) atomicAdd(&Sg[tid], sS[tid]);
  __syncthreads();  // drains global atomics before the flag

  if (tid == 0) {
    __threadfence();
    unsigned old = atomicAdd(ctr, 1u);
    if (old == (unsigned)(gridDim.x - 1)) {
      __threadfence();
      const float w = wv[0];
#pragma unroll
      for (int b = 0; b < 8; ++b) {
        float s = atomicAdd(&Sg[b], 0.f);  // coherent read
        out[b] = w * sqrtf(s) * (float)NVERT;
      }
    }
  }
}

extern "C" void kernel_launch(void* const* d_in, const int* in_sizes, int n_in,
                              void* d_out, int out_size, void* d_ws, size_t ws_size,
                              hipStream_t stream) {
  const float* x  = (const float*)d_in[0];   // (8, 10000, 3) fp32
  const float* L  = (const float*)d_in[1];   // (10000, 10000) fp32
  const float* wv = (const float*)d_in[2];   // (1,) fp32
  float* out = (float*)d_out;                // (8,) fp32

  float* C       = (float*)d_ws;                         // 240000 floats
  float* Sg      = (float*)((char*)d_ws + 960000);       // 8 floats
  unsigned* ctr  = (unsigned*)((char*)d_ws + 960032);    // counter

  hipMemsetAsync(d_ws, 0, 960064, stream);
  lap_main<<<GRID1, 256, 0, stream>>>(x, L, C);
  lap_reduce<<<GRID2, 256, 0, stream>>>(C, wv, out, Sg, ctr);
}

// Round 2
// 562.786 us; speedup vs baseline: 2.4909x; 2.4909x over previous
//
#include <hip/hip_runtime.h>
#include <math.h>

// LaplacianLoss: out[b] = vertex_weight * ||L @ x[b]||_F * NV
// L: 10000x10000 fp32, streamed once (~400 MB from HBM; poison evicts L3).
// Round-4 structure: pipelined streaming skinny GEMM, spill-free.
//  - x tile staged in LDS via global_load_lds width=16 (zero staging VGPRs),
//    DOUBLE-buffered -> ONE barrier per tile (round-0 had two).
//  - L fragments register-double-buffered: next tile's 4x float4 issued
//    right after the barrier, consumed next iteration; the ~800cy of
//    FMA+LDS-read compute covers the ~900cy HBM latency.
//  - __launch_bounds__(256,2): 256-VGPR cap. Peak pressure ~160 (acc 96 +
//    Lv/Ln 32 + xv 12 + addr). Round-1's spill (VGPR=84, 2.1 GB scratch
//    writes) came from the (256,3) 168-cap + 24 in-flight global x loads.
//  - grid = 625 row-groups x 4 j-groups; wave owns 4 rows, lane owns 4 cols.
//  - partials atomicAdd'ed into C[10000][24] (sum over j BEFORE squaring),
//    lap_reduce squares + reduces + sqrt.

#define NVERT 10000
#define TJ 256
#define TPG 10
#define JG 4
#define RPW 4         // rows per wave
#define RPB 16        // rows per block (4 waves)
#define NROWG 625
#define GRID1 (NROWG * JG)
#define GRID2 40

__device__ __forceinline__ void async_cp16(float* lds, const float4* g) {
  __builtin_amdgcn_global_load_lds(
      (const __attribute__((address_space(1))) void*)g,
      (__attribute__((address_space(3))) void*)lds, 16, 0, 0);
}

__global__ __launch_bounds__(256, 2) void lap_main(
    const float* __restrict__ x, const float* __restrict__ L,
    float* __restrict__ C) {
  // two 6144-float x-tile buffers ([b][192 float4] each); epilogue reuses buf0
  __shared__ __align__(16) float smem[12288];

  const int tid  = threadIdx.x;
  const int lane = tid & 63;
  const int wave = tid >> 6;
  const int rg   = blockIdx.x >> 2;   // row-group
  const int jg   = blockIdx.x & 3;    // j-group
  const int row0 = rg * RPB + wave * RPW;

  __align__(16) float acc[RPW][24];
#pragma unroll
  for (int r = 0; r < RPW; ++r)
#pragma unroll
    for (int n = 0; n < 24; ++n) acc[r][n] = 0.f;

  const int jbase = jg * (TPG * TJ);
  const int nT    = (jg == JG - 1) ? (TPG - 1) : TPG;  // full 256-col tiles
  const int xb4   = (jbase * 3) >> 2;                  // float4 offset of j-group in x row-space

  const float4* __restrict__ xg = (const float4*)x;    // [b][7500 float4]
  const float*  Lp = L + (long)row0 * NVERT + jbase + 4 * lane;

  // ---- stage tile 0 into buf 0 (async, drained by first barrier) ----
  // dest: wave-uniform base + lane*16B (required by global_load_lds).
  if (tid < 192) {
#pragma unroll
    for (int b = 0; b < 8; ++b)
      async_cp16(smem + b * 768 + tid * 4, xg + (long)b * 7500 + xb4 + tid);
  }

  // ---- register double-buffer for L fragments ----
  float4 Lv[RPW], Ln[RPW];
#pragma unroll
  for (int r = 0; r < RPW; ++r) {
    Lv[r] = *(const float4*)(Lp + (long)r * NVERT);
    Ln[r] = Lv[r];
  }

  for (int t = 0; t < nT; ++t) {
    __syncthreads();  // tile t staging + tile t L-prefetch complete

    if (t + 1 < nT) {
      // L prefetch FIRST (so the end-of-iter Lv=Ln wait has min vmcnt depth)
#pragma unroll
      for (int r = 0; r < RPW; ++r)
        Ln[r] = *(const float4*)(Lp + (long)r * NVERT + (t + 1) * TJ);
      const int sel = (t + 1) & 1;
      if (tid < 192) {
#pragma unroll
        for (int b = 0; b < 8; ++b)
          async_cp16(smem + sel * 6144 + b * 768 + tid * 4,
                     xg + (long)b * 7500 + xb4 + (t + 1) * 192 + tid);
      }
    }

    const float* xs = smem + (t & 1) * 6144 + 12 * lane;
#pragma unroll
    for (int b = 0; b < 8; ++b) {
      const float4 x0 = *(const float4*)(xs + b * 768);
      const float4 x1 = *(const float4*)(xs + b * 768 + 4);
      const float4 x2 = *(const float4*)(xs + b * 768 + 8);
      const float xv[12] = {x0.x, x0.y, x0.z, x0.w, x1.x, x1.y,
                            x1.z, x1.w, x2.x, x2.y, x2.z, x2.w};
#pragma unroll
      for (int r = 0; r < RPW; ++r) {
        const float* lv = (const float*)&Lv[r];
#pragma unroll
        for (int jj = 0; jj < 4; ++jj)
#pragma unroll
          for (int k = 0; k < 3; ++k)
            acc[r][b * 3 + k] += lv[jj] * xv[jj * 3 + k];
      }
    }

#pragma unroll
    for (int r = 0; r < RPW; ++r) Lv[r] = Ln[r];
  }

  // ---- tail: columns 9984..9999 (jg==3 only), 16 lanes x 1 column ----
  if (jg == JG - 1 && lane < 16) {
    const int col = jbase + (TPG - 1) * TJ + lane;
    float Lt[RPW];
#pragma unroll
    for (int r = 0; r < RPW; ++r)
      Lt[r] = L[(long)(row0 + r) * NVERT + col];
#pragma unroll
    for (int b = 0; b < 8; ++b) {
      const float* xb = x + (long)(b * NVERT + col) * 3;
      const float x0 = xb[0], x1 = xb[1], x2 = xb[2];
#pragma unroll
      for (int r = 0; r < RPW; ++r) {
        acc[r][b * 3 + 0] += Lt[r] * x0;
        acc[r][b * 3 + 1] += Lt[r] * x1;
        acc[r][b * 3 + 2] += Lt[r] * x2;
      }
    }
  }

  // ---- epilogue: cross-lane sum per (row, n), atomic into C ----
  // 4 rounds; wave w dumps 64 lanes x 96 floats at stride 100 (conflict-free:
  // 100 mod 32 = 4 -> 8 lanes cover all 32 banks), threads<96 sum 64 lanes.
  for (int w = 0; w < 4; ++w) {
    __syncthreads();
    if (wave == w) {
#pragma unroll
      for (int r = 0; r < RPW; ++r)
#pragma unroll
        for (int c = 0; c < 6; ++c)
          *(float4*)&smem[lane * 100 + r * 24 + c * 4] = *(float4*)&acc[r][c * 4];
    }
    __syncthreads();
    if (tid < 96) {
      float s = 0.f;
#pragma unroll
      for (int l = 0; l < 64; ++l) s += smem[l * 100 + tid];
      const int row = rg * RPB + w * RPW + tid / 24;
      atomicAdd(&C[row * 24 + (tid % 24)], s);
    }
  }
}

__global__ __launch_bounds__(256) void lap_reduce(
    const float* __restrict__ C, const float* __restrict__ wv,
    float* __restrict__ out, float* __restrict__ Sg, unsigned* __restrict__ ctr) {
  __shared__ float sS[8];
  const int tid = threadIdx.x;
  if (tid < 8) sS[tid] = 0.f;
  __syncthreads();

  const int row = blockIdx.x * 256 + tid;  // one row per thread (10240 >= 10000)
  float pb[8] = {0.f, 0.f, 0.f, 0.f, 0.f, 0.f, 0.f, 0.f};
  if (row < NVERT) {
    const float* rp = C + (long)row * 24;
#pragma unroll
    for (int b = 0; b < 8; ++b) {
      float s = 0.f;
#pragma unroll
      for (int k = 0; k < 3; ++k) {
        float v = rp[b * 3 + k];
        s += v * v;
      }
      pb[b] = s;
    }
  }
#pragma unroll
  for (int b = 0; b < 8; ++b) atomicAdd(&sS[b], pb[b]);
  __syncthreads();
  if (tid < 8) atomicAdd(&Sg[tid], sS[tid]);
  __syncthreads();  // drains global atomics before the flag

  if (tid == 0) {
    __threadfence();
    unsigned old = atomicAdd(ctr, 1u);
    if (old == (unsigned)(gridDim.x - 1)) {
      __threadfence();
      const float w = wv[0];
#pragma unroll
      for (int b = 0; b < 8; ++b) {
        float s = atomicAdd(&Sg[b], 0.f);  // coherent read
        out[b] = w * sqrtf(s) * (float)NVERT;
      }
    }
  }
}

extern "C" void kernel_launch(void* const* d_in, const int* in_sizes, int n_in,
                              void* d_out, int out_size, void* d_ws, size_t ws_size,
                              hipStream_t stream) {
  const float* x  = (const float*)d_in[0];   // (8, 10000, 3) fp32
  const float* L  = (const float*)d_in[1];   // (10000, 10000) fp32
  const float* wv = (const float*)d_in[2];   // (1,) fp32
  float* out = (float*)d_out;                // (8,) fp32

  float* C       = (float*)d_ws;                         // 240000 floats
  float* Sg      = (float*)((char*)d_ws + 960000);       // 8 floats
  unsigned* ctr  = (unsigned*)((char*)d_ws + 960032);    // counter

  hipMemsetAsync(d_ws, 0, 960064, stream);
  lap_main<<<GRID1, 256, 0, stream>>>(x, L, C);
  lap_reduce<<<GRID2, 256, 0, stream>>>(C, wv, out, Sg, ctr);
}